// Round 1
// baseline (321.794 us; speedup 1.0000x reference)
//
#include <hip/hip_runtime.h>
#include <math.h>

// YOLO loss, one thread per (n, i, j) grid cell.
// ws[0..3] = {cls, noobj, reg, cont} partial sums (float, atomic-accumulated).

__global__ void k_zero(float* __restrict__ ws) {
    if (threadIdx.x < 4) ws[threadIdx.x] = 0.0f;
}

__global__ __launch_bounds__(256) void k_yolo(
    const float* __restrict__ pred,
    const float* __restrict__ tbox,
    const float* __restrict__ tcls,
    const int*   __restrict__ mask,
    float* __restrict__ ws,
    int n_cells)
{
    int idx = blockIdx.x * blockDim.x + threadIdx.x;
    float cls = 0.f, noobj = 0.f, reg = 0.f, cont = 0.f;
    if (idx < n_cells) {
        long long base = (long long)idx;
        // pred cell: 30 floats, base byte offset = idx*120 -> 8B aligned -> float2 x15
        const float2* p2 = reinterpret_cast<const float2*>(pred + base * 30);
        float p[30];
        #pragma unroll
        for (int i = 0; i < 15; ++i) {
            float2 v = p2[i];
            p[2*i]   = v.x;
            p[2*i+1] = v.y;
        }
        // target box: 16B aligned -> one float4
        float4 tb = reinterpret_cast<const float4*>(tbox)[base];
        bool m = mask[idx] != 0;
        if (m) {
            // ---- class loss: sum over 20 classes of (tc - pc)^2 ----
            const float4* tc4 = reinterpret_cast<const float4*>(tcls + base * 20);
            float s = 0.f;
            #pragma unroll
            for (int i = 0; i < 5; ++i) {
                float4 t = tc4[i];
                float d0 = t.x - p[10 + 4*i + 0];
                float d1 = t.y - p[10 + 4*i + 1];
                float d2 = t.z - p[10 + 4*i + 2];
                float d3 = t.w - p[10 + 4*i + 3];
                s += d0*d0 + d1*d1 + d2*d2 + d3*d3;
            }
            cls = s;
            // ---- IoU of both pred boxes vs target ----
            float txc = tb.x / 14.0f, tyc = tb.y / 14.0f;
            float t0 = txc - 0.5f * tb.z, t1 = tyc - 0.5f * tb.w;
            float t2 = txc + 0.5f * tb.z, t3 = tyc + 0.5f * tb.w;
            float area_t = (t2 - t0) * (t3 - t1);  // matches ref fp order
            float iou0, iou1;
            #pragma unroll
            for (int b = 0; b < 2; ++b) {
                float px = p[5*b+0] / 14.0f, py = p[5*b+1] / 14.0f;
                float pw = p[5*b+2],         ph = p[5*b+3];
                float q0 = px - 0.5f * pw, q1 = py - 0.5f * ph;
                float q2 = px + 0.5f * pw, q3 = py + 0.5f * ph;
                float lt0 = fmaxf(t0, q0), lt1 = fmaxf(t1, q1);
                float rb0 = fminf(t2, q2), rb1 = fminf(t3, q3);
                float w = fmaxf(rb0 - lt0, 0.f), h = fmaxf(rb1 - lt1, 0.f);
                float inter  = w * h;
                float area_p = (q2 - q0) * (q3 - q1);
                float v = inter / (area_t + area_p - inter);
                if (b == 0) iou0 = v; else iou1 = v;
            }
            // jnp.argmax picks first max on ties -> strict > for box 1
            int bi = (iou1 > iou0) ? 1 : 0;
            float biou = bi ? iou1 : iou0;
            float bx = p[5*bi+0], by = p[5*bi+1];
            float bw = p[5*bi+2], bh = p[5*bi+3], bc = p[5*bi+4];
            float dx = bx - tb.x, dy = by - tb.y;
            float swd = sqrtf(bw) - sqrtf(tb.z);
            float shd = sqrtf(bh) - sqrtf(tb.w);
            reg = 5.0f * (dx*dx + dy*dy + swd*swd + shd*shd);  // L_COORD
            float dco = biou - bc;
            cont = dco * dco;
        } else {
            noobj = 0.5f * (p[4]*p[4] + p[9]*p[9]);            // L_NOOBJ
        }
    }
    // ---- wave (64-lane) shuffle reduction ----
    #pragma unroll
    for (int off = 32; off > 0; off >>= 1) {
        cls   += __shfl_down(cls,   off, 64);
        noobj += __shfl_down(noobj, off, 64);
        reg   += __shfl_down(reg,   off, 64);
        cont  += __shfl_down(cont,  off, 64);
    }
    __shared__ float smem[4][4];   // [wave][term], 256 thr = 4 waves
    int lane = threadIdx.x & 63;
    int wv   = threadIdx.x >> 6;
    if (lane == 0) {
        smem[wv][0] = cls; smem[wv][1] = noobj;
        smem[wv][2] = reg; smem[wv][3] = cont;
    }
    __syncthreads();
    if (threadIdx.x == 0) {
        float a = 0.f, b = 0.f, c = 0.f, d = 0.f;
        #pragma unroll
        for (int w = 0; w < 4; ++w) {
            a += smem[w][0]; b += smem[w][1]; c += smem[w][2]; d += smem[w][3];
        }
        atomicAdd(&ws[0], a);
        atomicAdd(&ws[1], b);
        atomicAdd(&ws[2], c);
        atomicAdd(&ws[3], d);
    }
}

__global__ void k_final(const float* __restrict__ ws, float* __restrict__ out, float invN) {
    float cls = ws[0], noobj = ws[1], reg = ws[2], cont = ws[3];
    out[0] = (cls + noobj + reg + cont) * invN;  // total_loss
    out[1] = reg;                                 // reg_loss
    out[2] = cont;                                // containing_obj_loss
    out[3] = noobj;                               // no_obj_loss
    out[4] = cls;                                 // cls_loss
}

extern "C" void kernel_launch(void* const* d_in, const int* in_sizes, int n_in,
                              void* d_out, int out_size, void* d_ws, size_t ws_size,
                              hipStream_t stream) {
    const float* pred = (const float*)d_in[0];  // (N,14,14,30) f32
    const float* tbox = (const float*)d_in[1];  // (N,14,14,4)  f32
    const float* tcls = (const float*)d_in[2];  // (N,14,14,20) f32
    const int*   mask = (const int*)d_in[3];    // (N,14,14)    bool->int
    float* out = (float*)d_out;                 // 5 scalars
    float* ws  = (float*)d_ws;

    int n_cells = in_sizes[3];                  // N * 14 * 14
    int N       = in_sizes[0] / (14 * 14 * 30); // batch size

    hipLaunchKernelGGL(k_zero, dim3(1), dim3(64), 0, stream, ws);
    int blocks = (n_cells + 255) / 256;
    hipLaunchKernelGGL(k_yolo, dim3(blocks), dim3(256), 0, stream,
                       pred, tbox, tcls, mask, ws, n_cells);
    hipLaunchKernelGGL(k_final, dim3(1), dim3(1), 0, stream, ws, out, 1.0f / (float)N);
}

// Round 2
// 201.961 us; speedup vs baseline: 1.5933x; 1.5933x over previous
//
#include <hip/hip_runtime.h>
#include <math.h>

// YOLO loss — coalesced-staging version.
// Each wave owns 64 consecutive cells. pred (30 f32/cell) is staged into LDS
// with contiguous float4 loads; per-cell box math reads LDS; class loss is
// computed by sweeping the wave's contiguous tcls span (order-free sum).
// Blocks write float4 partials {cls,noobj,reg,cont} to ws; k_final reduces.

#define BLOCK 256
#define WPB 4            // waves per block
#define CPW 64           // cells per wave

__global__ __launch_bounds__(BLOCK) void k_yolo(
    const float*  __restrict__ pred,
    const float4* __restrict__ tbox4,
    const float4* __restrict__ tcls4,
    const int*    __restrict__ mask,
    float4*       __restrict__ partial,
    int n_cells)
{
    __shared__ float sp[WPB][CPW * 30];     // 30720 B
    const int tid  = threadIdx.x;
    const int lane = tid & 63;
    const int w    = tid >> 6;
    const long long cell0 = ((long long)blockIdx.x * WPB + w) * CPW;

    float cls = 0.f, noobj = 0.f, reg = 0.f, cont = 0.f;

    // ---- stage pred tile: 64 cells * 30 f32 = 480 float4, coalesced ----
    int mflag = 0;
    if (cell0 < n_cells) {
        const float4* p4 = reinterpret_cast<const float4*>(pred + cell0 * 30);
        float4* s4 = reinterpret_cast<float4*>(sp[w]);
        #pragma unroll
        for (int i = 0; i < 8; ++i) {
            int k = lane + i * 64;
            if (k < 480) s4[k] = p4[k];
        }
        long long cell = cell0 + lane;
        if (cell < (long long)n_cells) mflag = mask[cell];
    }
    __syncthreads();   // make staged LDS visible (cross-lane deps invisible to compiler)

    // ---- per-lane box terms ----
    if (cell0 + lane < (long long)n_cells) {
        const float2* pc2 = reinterpret_cast<const float2*>(sp[w] + lane * 30);
        float2 v0 = pc2[0], v1 = pc2[1], v2 = pc2[2], v3 = pc2[3], v4 = pc2[4];
        // p0..p9: box0 = (v0.x,v0.y,v1.x,v1.y,conf v2.x); box1 = (v2.y,v3.x,v3.y,v4.x,conf v4.y)
        float4 tb = tbox4[cell0 + lane];
        if (mflag) {
            float txc = tb.x / 14.0f, tyc = tb.y / 14.0f;
            float t0 = txc - 0.5f * tb.z, t1 = tyc - 0.5f * tb.w;
            float t2 = txc + 0.5f * tb.z, t3 = tyc + 0.5f * tb.w;
            float area_t = (t2 - t0) * (t3 - t1);
            float bx[2] = { v0.x, v2.y }, by[2] = { v0.y, v3.x };
            float bw[2] = { v1.x, v3.y }, bh[2] = { v1.y, v4.x };
            float bcf[2] = { v2.x, v4.y };
            float iou[2];
            #pragma unroll
            for (int b = 0; b < 2; ++b) {
                float px = bx[b] / 14.0f, py = by[b] / 14.0f;
                float q0 = px - 0.5f * bw[b], q1 = py - 0.5f * bh[b];
                float q2 = px + 0.5f * bw[b], q3 = py + 0.5f * bh[b];
                float lt0 = fmaxf(t0, q0), lt1 = fmaxf(t1, q1);
                float rb0 = fminf(t2, q2), rb1 = fminf(t3, q3);
                float ww = fmaxf(rb0 - lt0, 0.f), hh = fmaxf(rb1 - lt1, 0.f);
                float inter = ww * hh;
                float area_p = (q2 - q0) * (q3 - q1);
                iou[b] = inter / (area_t + area_p - inter);
            }
            int bi = (iou[1] > iou[0]) ? 1 : 0;   // first-max tie rule
            float dx = bx[bi] - tb.x, dy = by[bi] - tb.y;
            float swd = sqrtf(bw[bi]) - sqrtf(tb.z);
            float shd = sqrtf(bh[bi]) - sqrtf(tb.w);
            reg = 5.0f * (dx*dx + dy*dy + swd*swd + shd*shd);
            float dco = iou[bi] - bcf[bi];
            cont = dco * dco;
        } else {
            noobj = 0.5f * (v2.x * v2.x + v4.y * v4.y);
        }
    }

    // ---- class loss: sweep wave's contiguous tcls span (320 float4) ----
    if (cell0 < n_cells) {
        const float4* t4 = tcls4 + cell0 * 5;
        #pragma unroll
        for (int i = 0; i < 5; ++i) {
            int j = lane + i * 64;        // 0..319
            int c = j / 5;                // local cell 0..63
            int q = j - 5 * c;            // float4 index within cell, 0..4
            int mc = __shfl(mflag, c, 64);
            if (mc) {
                float4 t = t4[j];
                const float2* s2 = reinterpret_cast<const float2*>(sp[w] + c * 30 + 10 + q * 4);
                float2 a = s2[0], b = s2[1];
                float d0 = t.x - a.x, d1 = t.y - a.y;
                float d2 = t.z - b.x, d3 = t.w - b.y;
                cls += d0*d0 + d1*d1 + d2*d2 + d3*d3;
            }
        }
    }

    // ---- wave shuffle reduce, then block reduce, store partial ----
    #pragma unroll
    for (int off = 32; off; off >>= 1) {
        cls   += __shfl_down(cls,   off, 64);
        noobj += __shfl_down(noobj, off, 64);
        reg   += __shfl_down(reg,   off, 64);
        cont  += __shfl_down(cont,  off, 64);
    }
    __shared__ float4 swr[WPB];
    if (lane == 0) swr[w] = make_float4(cls, noobj, reg, cont);
    __syncthreads();
    if (tid == 0) {
        float4 a = swr[0];
        #pragma unroll
        for (int i = 1; i < WPB; ++i) {
            float4 b = swr[i];
            a.x += b.x; a.y += b.y; a.z += b.z; a.w += b.w;
        }
        partial[blockIdx.x] = a;
    }
}

__global__ __launch_bounds__(BLOCK) void k_final(
    const float4* __restrict__ partial, int nblocks,
    float* __restrict__ out, float invN)
{
    float4 acc = make_float4(0.f, 0.f, 0.f, 0.f);
    for (int b = threadIdx.x; b < nblocks; b += BLOCK) {
        float4 v = partial[b];
        acc.x += v.x; acc.y += v.y; acc.z += v.z; acc.w += v.w;
    }
    #pragma unroll
    for (int off = 32; off; off >>= 1) {
        acc.x += __shfl_down(acc.x, off, 64);
        acc.y += __shfl_down(acc.y, off, 64);
        acc.z += __shfl_down(acc.z, off, 64);
        acc.w += __shfl_down(acc.w, off, 64);
    }
    __shared__ float4 sw[WPB];
    int lane = threadIdx.x & 63, w = threadIdx.x >> 6;
    if (lane == 0) sw[w] = acc;
    __syncthreads();
    if (threadIdx.x == 0) {
        float cls = 0.f, noobj = 0.f, reg = 0.f, cont = 0.f;
        #pragma unroll
        for (int i = 0; i < WPB; ++i) {
            cls += sw[i].x; noobj += sw[i].y; reg += sw[i].z; cont += sw[i].w;
        }
        out[0] = (cls + noobj + reg + cont) * invN;
        out[1] = reg;
        out[2] = cont;
        out[3] = noobj;
        out[4] = cls;
    }
}

extern "C" void kernel_launch(void* const* d_in, const int* in_sizes, int n_in,
                              void* d_out, int out_size, void* d_ws, size_t ws_size,
                              hipStream_t stream) {
    const float*  pred  = (const float*)d_in[0];   // (N,14,14,30) f32
    const float4* tbox4 = (const float4*)d_in[1];  // (N,14,14,4)  f32
    const float4* tcls4 = (const float4*)d_in[2];  // (N,14,14,20) f32
    const int*    mask  = (const int*)d_in[3];     // (N,14,14)    int32 (verified R1)
    float* out = (float*)d_out;
    float4* partial = (float4*)d_ws;

    int n_cells = in_sizes[3];
    int N = in_sizes[0] / (14 * 14 * 30);
    int nblocks = (n_cells + BLOCK - 1) / BLOCK;

    hipLaunchKernelGGL(k_yolo, dim3(nblocks), dim3(BLOCK), 0, stream,
                       pred, tbox4, tcls4, mask, partial, n_cells);
    hipLaunchKernelGGL(k_final, dim3(1), dim3(BLOCK), 0, stream,
                       partial, nblocks, out, 1.0f / (float)N);
}